// Round 8
// baseline (283.959 us; speedup 1.0000x reference)
//
#include <hip/hip_runtime.h>

// VQ via MFMA: x (32,64,64,64) fp32 NCHW, embed (512,64) fp32.
// bf16 hi/lo split (6 MFMA passes, fp32 acc) for PRUNING only; candidates
// within EPS of the row-min are re-checked in exact fp32 (same fmaf order as
// the R1-passing scalar kernel) -> argmin matches np (absmax 0 in R6/R7).
//
// R8 = R6 ownership + R7 plumbing:
//  - wave processes ALL 64 rows x its 128 codes -> 4x B reuse per load
//    (R7's 1x reuse made the loop L2-latency-bound: MfmaUtil 11->6.5%).
//  - distance-2 double-buffered B prefetch (~620 cyc cover >= L2 latency).
//  - XsH/XsL staged in LDS once (conversion shared); A-frags via ds_read_b128.
//  - float-domain min1/min2 keys: dist with low 9 mantissa bits = code id
//    (quantum 0.016 << EPS); fminf/fmaxf update, 6 VALU/elem.
//  - candidates filtered vs WAVE-local row-min (no cross-wave reduce barrier;
//    extra candidates just lose the exact-recheck atomicMin). Two barriers.

#define VQ_N 131072
#define VQ_D 64
#define VQ_K 512
#define VQ_HW 4096
#define ROWS 64          // rows per block
#define EPS 0.25f        // prune margin; approx error ~1e-3, key quantum 0.016
#define QW 512           // queue entries per wave
#define XH_STR 72        // shorts/row (64+8 pad), 144B stride (16B-aligned)
#define X32_STR 68       // floats/row, 16B-aligned

typedef __attribute__((ext_vector_type(8))) short short8;
typedef __attribute__((ext_vector_type(4))) float f32x4;

static __device__ __forceinline__ unsigned short f2bf(float f) {
    unsigned u = __float_as_uint(f);
    unsigned r = (u + 0x7fffu + ((u >> 16) & 1u)) >> 16;   // round-nearest-even
    return (unsigned short)r;
}
static __device__ __forceinline__ float bf2f(unsigned short h) {
    return __uint_as_float(((unsigned)h) << 16);
}
// order-preserving float->uint for the exact-recheck u64 key
static __device__ __forceinline__ unsigned fenc(float f) {
    unsigned u = __float_as_uint(f);
    return u ^ ((unsigned)(((int)u) >> 31) | 0x80000000u);
}
// clear low 9 mantissa bits (monotone-ish decode of embedded-index keys)
static __device__ __forceinline__ float clr9(float f) {
    return __uint_as_float(__float_as_uint(f) & 0xFFFFFE00u);
}

// prep: embed fp32 -> bf16 hi/lo (EH, EL); first 512 threads also do e_sq
__global__ __launch_bounds__(256) void vq_prep_kernel(
    const float* __restrict__ embed,
    unsigned short* __restrict__ EH, unsigned short* __restrict__ EL,
    float* __restrict__ esq) {
    int g = blockIdx.x * 256 + threadIdx.x;   // 32768 elems
    float f = embed[g];
    unsigned short h = f2bf(f);
    EH[g] = h;
    EL[g] = f2bf(f - bf2f(h));
    if (g < VQ_K) {
        const float* e = embed + g * VQ_D;
        float p0 = 0.f, p1 = 0.f, p2 = 0.f, p3 = 0.f;
#pragma unroll
        for (int d = 0; d < VQ_D; d += 4) {
            p0 = fmaf(e[d + 0], e[d + 0], p0);
            p1 = fmaf(e[d + 1], e[d + 1], p1);
            p2 = fmaf(e[d + 2], e[d + 2], p2);
            p3 = fmaf(e[d + 3], e[d + 3], p3);
        }
        esq[g] = (p0 + p1) + (p2 + p3);
    }
}

// load B fragments for local code-tile nt (16 codes of this wave's 128)
#define LOADB(nt, bf) {                                            \
    int _eo = (nb + ((nt) << 4) + lrow) * VQ_D + (quad << 3);      \
    BH0[bf] = *(const short8*)&EH[_eo];                            \
    BH1[bf] = *(const short8*)&EH[_eo + 32];                       \
    BL0[bf] = *(const short8*)&EL[_eo];                            \
    BL1[bf] = *(const short8*)&EL[_eo + 32]; }

// 6-MFMA hi/lo dist for (row-tile rt, code-tile nt) + float-key min update
#define PROCESS(nt, rt, bf) {                                                  \
    f32x4 acc = {0.f, 0.f, 0.f, 0.f};                                          \
    acc = __builtin_amdgcn_mfma_f32_16x16x32_bf16(AH[rt][0], BH0[bf], acc, 0, 0, 0); \
    acc = __builtin_amdgcn_mfma_f32_16x16x32_bf16(AH[rt][1], BH1[bf], acc, 0, 0, 0); \
    acc = __builtin_amdgcn_mfma_f32_16x16x32_bf16(AH[rt][0], BL0[bf], acc, 0, 0, 0); \
    acc = __builtin_amdgcn_mfma_f32_16x16x32_bf16(AH[rt][1], BL1[bf], acc, 0, 0, 0); \
    acc = __builtin_amdgcn_mfma_f32_16x16x32_bf16(AL[rt][0], BH0[bf], acc, 0, 0, 0); \
    acc = __builtin_amdgcn_mfma_f32_16x16x32_bf16(AL[rt][1], BH1[bf], acc, 0, 0, 0); \
    unsigned _nn = (unsigned)(nb + ((nt) << 4) + lrow);  /* global code id */  \
    _Pragma("unroll")                                                          \
    for (int i = 0; i < 4; ++i) {      /* C: col(n)=lane&15, row=quad*4+i */   \
        float v = fmaf(-2.f, acc[i], esqv[nt]);                                \
        float kf = __uint_as_float((__float_as_uint(v) & 0xFFFFFE00u) | _nn);  \
        float hi = fmaxf(m1[rt][i], kf);                                       \
        m1[rt][i] = fminf(m1[rt][i], kf);                                      \
        m2[rt][i] = fminf(m2[rt][i], hi);                                      \
    } }

__global__ __launch_bounds__(256, 3) void vq_mfma_kernel(
    const float* __restrict__ x, const float* __restrict__ embed,
    const float* __restrict__ esq,
    const unsigned short* __restrict__ EH, const unsigned short* __restrict__ EL,
    float* __restrict__ out_q, float* __restrict__ out_idx) {
    __shared__ __align__(16) unsigned short XsH[ROWS * XH_STR];  // 9216 B
    __shared__ __align__(16) unsigned short XsL[ROWS * XH_STR];  // 9216 B
    __shared__ __align__(16) float Xs32[ROWS * X32_STR];         // 17408 B
    __shared__ unsigned long long row_best[ROWS];                // 512 B
    __shared__ int qcnt[4];
    __shared__ unsigned short qbuf[4 * QW];                      // 4096 B

    const int t   = threadIdx.x;
    const int n0  = blockIdx.x * ROWS;
    const int b   = n0 >> 12;        // 64 | 4096 -> block stays in one image
    const int hw0 = n0 & 4095;

    if (t < ROWS) row_best[t] = ~0ull;
    if (t < 4) qcnt[t] = 0;

    // ---- stage X: fp32 + bf16 hi/lo; global loads coalesced over hw ----
    {
        const int hw = t & 63;
        const int d0 = (t >> 6) * 16;
        const float* xb = x + (size_t)b * (VQ_D * VQ_HW) + hw0 + hw;
        short8 H0, H1, L0, L1;
#pragma unroll
        for (int dd = 0; dd < 8; ++dd) {
            float f = xb[(d0 + dd) * VQ_HW];
            Xs32[hw * X32_STR + d0 + dd] = f;
            unsigned short hb = f2bf(f);
            H0[dd] = (short)hb; L0[dd] = (short)f2bf(f - bf2f(hb));
        }
#pragma unroll
        for (int dd = 0; dd < 8; ++dd) {
            float f = xb[(d0 + 8 + dd) * VQ_HW];
            Xs32[hw * X32_STR + d0 + 8 + dd] = f;
            unsigned short hb = f2bf(f);
            H1[dd] = (short)hb; L1[dd] = (short)f2bf(f - bf2f(hb));
        }
        *(short8*)&XsH[hw * XH_STR + d0]     = H0;
        *(short8*)&XsH[hw * XH_STR + d0 + 8] = H1;
        *(short8*)&XsL[hw * XH_STR + d0]     = L0;
        *(short8*)&XsL[hw * XH_STR + d0 + 8] = L1;
    }
    __syncthreads();   // barrier 1

    const int lane = t & 63;
    const int wave = t >> 6;
    const int lrow = lane & 15;
    const int quad = lane >> 4;
    const int nb   = wave * 128;     // this wave's 128 codes

    // ---- A fragments for all 4 row-tiles: A[m=lrow][k=quad*8+j] ----
    short8 AH[4][2], AL[4][2];
#pragma unroll
    for (int rt = 0; rt < 4; ++rt)
#pragma unroll
        for (int kk = 0; kk < 2; ++kk) {
            int off = (rt * 16 + lrow) * XH_STR + kk * 32 + quad * 8;
            AH[rt][kk] = *(const short8*)&XsH[off];
            AL[rt][kk] = *(const short8*)&XsL[off];
        }

    float esqv[8];
#pragma unroll
    for (int nt = 0; nt < 8; ++nt) esqv[nt] = esq[nb + nt * 16 + lrow];

    float m1[4][4], m2[4][4];
#pragma unroll
    for (int rt = 0; rt < 4; ++rt)
#pragma unroll
        for (int i = 0; i < 4; ++i) {
            m1[rt][i] = __uint_as_float(0x7F800000u);   // +inf (low 9 bits 0)
            m2[rt][i] = __uint_as_float(0x7F800000u);
        }

    // ---- main loop: 8 code-tiles, distance-2 double-buffered B prefetch ----
    short8 BH0[2], BH1[2], BL0[2], BL1[2];
    LOADB(0, 0)
    LOADB(1, 1)
#pragma unroll
    for (int nt = 0; nt < 8; ++nt) {
        const int bf = nt & 1;
        PROCESS(nt, 0, bf)
        PROCESS(nt, 1, bf)
        PROCESS(nt, 2, bf)
        PROCESS(nt, 3, bf)
        if (nt + 2 < 8) LOADB(nt + 2, bf)
    }

    // ---- wave-local row-min over the 16 n-lanes (per rt,i) ----
    float g1[4][4];
#pragma unroll
    for (int rt = 0; rt < 4; ++rt)
#pragma unroll
        for (int i = 0; i < 4; ++i) g1[rt][i] = m1[rt][i];
#pragma unroll
    for (int s = 1; s <= 8; s <<= 1)
#pragma unroll
        for (int rt = 0; rt < 4; ++rt)
#pragma unroll
            for (int i = 0; i < 4; ++i)
                g1[rt][i] = fminf(g1[rt][i], __shfl_xor(g1[rt][i], s));

    // ---- push candidates (within EPS of wave-local row-min) ----
#pragma unroll
    for (int rt = 0; rt < 4; ++rt)
#pragma unroll
        for (int i = 0; i < 4; ++i) {
            int m = rt * 16 + quad * 4 + i;            // block-local row 0..63
            float thr = clr9(g1[rt][i]) + EPS;
            if (clr9(m1[rt][i]) <= thr) {
                int id = atomicAdd(&qcnt[wave], 1);
                if (id < QW)
                    qbuf[wave * QW + id] = (unsigned short)
                        (((unsigned)m << 9) | (__float_as_uint(m1[rt][i]) & 511u));
            }
            if (clr9(m2[rt][i]) <= thr) {
                int id = atomicAdd(&qcnt[wave], 1);
                if (id < QW)
                    qbuf[wave * QW + id] = (unsigned short)
                        (((unsigned)m << 9) | (__float_as_uint(m2[rt][i]) & 511u));
            }
        }
    asm volatile("s_waitcnt lgkmcnt(0)");   // wave-local queue visible

    // ---- exact fp32 recheck (same fmaf order as R1 kernel), wave-local ----
    int qc = atomicAdd(&qcnt[wave], 0);
    if (qc > QW) qc = QW;
    for (int qi = lane; qi < qc; qi += 64) {
        unsigned e = qbuf[wave * QW + qi];
        int m = (int)(e >> 9), n = (int)(e & 511u);
        const float4* er = (const float4*)(embed + n * VQ_D);
        const float4* xr = (const float4*)&Xs32[m * X32_STR];
        float dot = 0.f;
#pragma unroll
        for (int d4 = 0; d4 < 16; ++d4) {
            float4 ev = er[d4]; float4 xv = xr[d4];
            dot = fmaf(xv.x, ev.x, dot);
            dot = fmaf(xv.y, ev.y, dot);
            dot = fmaf(xv.z, ev.z, dot);
            dot = fmaf(xv.w, ev.w, dot);
        }
        float v = fmaf(-2.f, dot, esq[n]);
        unsigned long long key =
            (((unsigned long long)fenc(v)) << 32) | (unsigned)n;
        atomicMin(&row_best[m], key);   // exact order; equal dist -> smaller n
    }
    __syncthreads();   // barrier 2: all waves' rechecks done

    // ---- outputs: indices + fully-coalesced quantized rows ----
    if (t < ROWS) out_idx[n0 + t] = (float)(unsigned)(row_best[t] & 0xffffffffu);

#pragma unroll
    for (int it = 0; it < 4; ++it) {
        int o   = it * 1024 + t * 4;          // 64 rows x 64 floats, contiguous
        int row = o >> 6;
        int col = o & 63;
        unsigned k = (unsigned)(row_best[row] & 0xffffffffu);
        float4 val = *(const float4*)(embed + k * VQ_D + col);
        *(float4*)(out_q + (size_t)n0 * VQ_D + o) = val;
    }
}

extern "C" void kernel_launch(void* const* d_in, const int* in_sizes, int n_in,
                              void* d_out, int out_size, void* d_ws, size_t ws_size,
                              hipStream_t stream) {
    const float* x     = (const float*)d_in[0];
    const float* embed = (const float*)d_in[1];
    float* out_q   = (float*)d_out;
    float* out_idx = (float*)d_out + (size_t)VQ_N * VQ_D;

    float* esq          = (float*)d_ws;                          // 512 f
    unsigned short* EH  = (unsigned short*)((char*)d_ws + 2048);
    unsigned short* EL  = (unsigned short*)((char*)d_ws + 2048 + VQ_K * VQ_D * 2);

    vq_prep_kernel<<<(VQ_K * VQ_D) / 256, 256, 0, stream>>>(embed, EH, EL, esq);
    vq_mfma_kernel<<<VQ_N / ROWS, 256, 0, stream>>>(x, embed, esq, EH, EL, out_q, out_idx);
}

// Round 9
// 137.891 us; speedup vs baseline: 2.0593x; 2.0593x over previous
//
#include <hip/hip_runtime.h>

// VQ via MFMA: x (32,64,64,64) fp32 NCHW, embed (512,64) fp32.
// Approx dists via bf16 MFMA (A = x-hi only; B = e-hi + e-lo -> 4 MFMAs,
// fp32 acc; missing term sum(x_lo*e) max ~0.03 << EPS) used for PRUNING;
// candidates within EPS of the wave-local row-min are re-checked in exact
// fp32 (same fmaf order as the R1-passing scalar kernel) -> argmin == np.
//
// R9 = R8 spill-proofed (R8: #pragma unroll failed on the big nt-loop ->
// BH0[bf]/esqv[nt] dynamic-indexed -> scratch arrays -> FETCH 263MB/WRITE
// 526MB, 243us). Rules: named a/b prefetch regs (no arrays), es loaded per
// tile (no esqv[] array), literal-constant indices only, #pragma unroll 1
// step-2 loop. Plus: AL pass dropped (4 MFMAs, A-frags 32 VGPRs, no XsL ->
// LDS 31.3KB -> 5 blocks/CU). Spill tripwire: WRITE_SIZE must stay ~33MB.

#define VQ_N 131072
#define VQ_D 64
#define VQ_K 512
#define VQ_HW 4096
#define ROWS 64          // rows per block
#define EPS 0.25f        // prune margin; approx err max ~0.03, key quantum 0.016
#define QW 512           // queue entries per wave
#define XH_STR 72        // shorts/row (64+8 pad), 144B stride (16B-aligned)
#define X32_STR 68       // floats/row, 16B-aligned

typedef __attribute__((ext_vector_type(8))) short short8;
typedef __attribute__((ext_vector_type(4))) float f32x4;

static __device__ __forceinline__ unsigned short f2bf(float f) {
    unsigned u = __float_as_uint(f);
    unsigned r = (u + 0x7fffu + ((u >> 16) & 1u)) >> 16;   // round-nearest-even
    return (unsigned short)r;
}
static __device__ __forceinline__ float bf2f(unsigned short h) {
    return __uint_as_float(((unsigned)h) << 16);
}
// order-preserving float->uint for the exact-recheck u64 key
static __device__ __forceinline__ unsigned fenc(float f) {
    unsigned u = __float_as_uint(f);
    return u ^ ((unsigned)(((int)u) >> 31) | 0x80000000u);
}
// clear low 9 mantissa bits (decode of embedded-index float keys)
static __device__ __forceinline__ float clr9(float f) {
    return __uint_as_float(__float_as_uint(f) & 0xFFFFFE00u);
}

// prep: embed fp32 -> bf16 hi/lo (EH, EL); first 512 threads also do e_sq
__global__ __launch_bounds__(256) void vq_prep_kernel(
    const float* __restrict__ embed,
    unsigned short* __restrict__ EH, unsigned short* __restrict__ EL,
    float* __restrict__ esq) {
    int g = blockIdx.x * 256 + threadIdx.x;   // 32768 elems
    float f = embed[g];
    unsigned short h = f2bf(f);
    EH[g] = h;
    EL[g] = f2bf(f - bf2f(h));
    if (g < VQ_K) {
        const float* e = embed + g * VQ_D;
        float p0 = 0.f, p1 = 0.f, p2 = 0.f, p3 = 0.f;
#pragma unroll
        for (int d = 0; d < VQ_D; d += 4) {
            p0 = fmaf(e[d + 0], e[d + 0], p0);
            p1 = fmaf(e[d + 1], e[d + 1], p1);
            p2 = fmaf(e[d + 2], e[d + 2], p2);
            p3 = fmaf(e[d + 3], e[d + 3], p3);
        }
        esq[g] = (p0 + p1) + (p2 + p3);
    }
}

// load B fragments + esq for local code-tile nt into NAMED regs (no arrays)
#define LOADB(nt, BH0, BH1, BL0, BL1, ES) {                        \
    int _eo = (nb + ((nt) << 4) + lrow) * VQ_D + (quad << 3);      \
    BH0 = *(const short8*)&EH[_eo];                                \
    BH1 = *(const short8*)&EH[_eo + 32];                           \
    BL0 = *(const short8*)&EL[_eo];                                \
    BL1 = *(const short8*)&EL[_eo + 32];                           \
    ES  = esq[nb + ((nt) << 4) + lrow]; }

// 4-MFMA dist (A-hi x B-hi + A-hi x B-lo) for row-tile rt + float-key update
#define PROCESS1(nt, rt, BH0, BH1, BL0, BL1, ES) {                             \
    f32x4 acc = {0.f, 0.f, 0.f, 0.f};                                          \
    acc = __builtin_amdgcn_mfma_f32_16x16x32_bf16(AH##rt##0, BH0, acc, 0, 0, 0); \
    acc = __builtin_amdgcn_mfma_f32_16x16x32_bf16(AH##rt##1, BH1, acc, 0, 0, 0); \
    acc = __builtin_amdgcn_mfma_f32_16x16x32_bf16(AH##rt##0, BL0, acc, 0, 0, 0); \
    acc = __builtin_amdgcn_mfma_f32_16x16x32_bf16(AH##rt##1, BL1, acc, 0, 0, 0); \
    unsigned _nn = (unsigned)(nb + ((nt) << 4) + lrow);  /* global code id */  \
    _Pragma("unroll")                                                          \
    for (int i = 0; i < 4; ++i) {      /* C: col(n)=lane&15, row=quad*4+i */   \
        float v = fmaf(-2.f, acc[i], ES);                                      \
        float kf = __uint_as_float((__float_as_uint(v) & 0xFFFFFE00u) | _nn);  \
        float hi = fmaxf(m1[rt][i], kf);                                       \
        m1[rt][i] = fminf(m1[rt][i], kf);                                      \
        m2[rt][i] = fminf(m2[rt][i], hi);                                      \
    } }

#define PROCESS4(nt, BH0, BH1, BL0, BL1, ES)     \
    PROCESS1(nt, 0, BH0, BH1, BL0, BL1, ES)      \
    PROCESS1(nt, 1, BH0, BH1, BL0, BL1, ES)      \
    PROCESS1(nt, 2, BH0, BH1, BL0, BL1, ES)      \
    PROCESS1(nt, 3, BH0, BH1, BL0, BL1, ES)

__global__ __launch_bounds__(256, 2) void vq_mfma_kernel(
    const float* __restrict__ x, const float* __restrict__ embed,
    const float* __restrict__ esq,
    const unsigned short* __restrict__ EH, const unsigned short* __restrict__ EL,
    float* __restrict__ out_q, float* __restrict__ out_idx) {
    __shared__ __align__(16) unsigned short XsH[ROWS * XH_STR];  // 9216 B
    __shared__ __align__(16) float Xs32[ROWS * X32_STR];         // 17408 B
    __shared__ unsigned long long row_best[ROWS];                // 512 B
    __shared__ int qcnt[4];
    __shared__ unsigned short qbuf[4 * QW];                      // 4096 B

    const int t   = threadIdx.x;
    const int n0  = blockIdx.x * ROWS;
    const int b   = n0 >> 12;        // 64 | 4096 -> block stays in one image
    const int hw0 = n0 & 4095;

    if (t < ROWS) row_best[t] = ~0ull;
    if (t < 4) qcnt[t] = 0;

    // ---- stage X: fp32 + bf16-hi; global loads coalesced over hw ----
    {
        const int hw = t & 63;
        const int d0 = (t >> 6) * 16;
        const float* xb = x + (size_t)b * (VQ_D * VQ_HW) + hw0 + hw;
        short8 H0, H1;
#pragma unroll
        for (int dd = 0; dd < 8; ++dd) {
            float f = xb[(d0 + dd) * VQ_HW];
            Xs32[hw * X32_STR + d0 + dd] = f;
            H0[dd] = (short)f2bf(f);
        }
#pragma unroll
        for (int dd = 0; dd < 8; ++dd) {
            float f = xb[(d0 + 8 + dd) * VQ_HW];
            Xs32[hw * X32_STR + d0 + 8 + dd] = f;
            H1[dd] = (short)f2bf(f);
        }
        *(short8*)&XsH[hw * XH_STR + d0]     = H0;
        *(short8*)&XsH[hw * XH_STR + d0 + 8] = H1;
    }
    __syncthreads();   // barrier 1

    const int lane = t & 63;
    const int wave = t >> 6;
    const int lrow = lane & 15;
    const int quad = lane >> 4;
    const int nb   = wave * 128;     // this wave's 128 codes

    // ---- A fragments (hi only), named regs: A[m=lrow][k=quad*8+j] ----
    short8 AH00, AH01, AH10, AH11, AH20, AH21, AH30, AH31;
#define LOADA(rt)                                                              \
    AH##rt##0 = *(const short8*)&XsH[(rt * 16 + lrow) * XH_STR + quad * 8];    \
    AH##rt##1 = *(const short8*)&XsH[(rt * 16 + lrow) * XH_STR + 32 + quad * 8];
    LOADA(0) LOADA(1) LOADA(2) LOADA(3)
#undef LOADA

    float m1[4][4], m2[4][4];
#pragma unroll
    for (int rt = 0; rt < 4; ++rt)
#pragma unroll
        for (int i = 0; i < 4; ++i) {
            m1[rt][i] = __uint_as_float(0x7F800000u);   // +inf (low 9 bits 0)
            m2[rt][i] = __uint_as_float(0x7F800000u);
        }

    // ---- main loop: 8 code-tiles, double-buffered NAMED-reg prefetch ----
    short8 bh0a, bh1a, bl0a, bl1a; float esa;
    short8 bh0b, bh1b, bl0b, bl1b; float esb;
    LOADB(0, bh0a, bh1a, bl0a, bl1a, esa)
#pragma unroll 1
    for (int nt = 0; nt < 8; nt += 2) {
        LOADB(nt + 1, bh0b, bh1b, bl0b, bl1b, esb)
        PROCESS4(nt, bh0a, bh1a, bl0a, bl1a, esa)
        int ntp = (nt + 2 < 8) ? nt + 2 : 7;    // clamped harmless reload
        LOADB(ntp, bh0a, bh1a, bl0a, bl1a, esa)
        PROCESS4(nt + 1, bh0b, bh1b, bl0b, bl1b, esb)
    }

    // ---- wave-local row-min over the 16 n-lanes (per rt,i) ----
    float g1[4][4];
#pragma unroll
    for (int rt = 0; rt < 4; ++rt)
#pragma unroll
        for (int i = 0; i < 4; ++i) g1[rt][i] = m1[rt][i];
#pragma unroll
    for (int s = 1; s <= 8; s <<= 1)
#pragma unroll
        for (int rt = 0; rt < 4; ++rt)
#pragma unroll
            for (int i = 0; i < 4; ++i)
                g1[rt][i] = fminf(g1[rt][i], __shfl_xor(g1[rt][i], s));

    // ---- push candidates (within EPS of wave-local row-min) ----
#pragma unroll
    for (int rt = 0; rt < 4; ++rt)
#pragma unroll
        for (int i = 0; i < 4; ++i) {
            int m = rt * 16 + quad * 4 + i;            // block-local row 0..63
            float thr = clr9(g1[rt][i]) + EPS;
            if (clr9(m1[rt][i]) <= thr) {
                int id = atomicAdd(&qcnt[wave], 1);
                if (id < QW)
                    qbuf[wave * QW + id] = (unsigned short)
                        (((unsigned)m << 9) | (__float_as_uint(m1[rt][i]) & 511u));
            }
            if (clr9(m2[rt][i]) <= thr) {
                int id = atomicAdd(&qcnt[wave], 1);
                if (id < QW)
                    qbuf[wave * QW + id] = (unsigned short)
                        (((unsigned)m << 9) | (__float_as_uint(m2[rt][i]) & 511u));
            }
        }
    asm volatile("s_waitcnt lgkmcnt(0)");   // wave-local queue visible

    // ---- exact fp32 recheck (same fmaf order as R1 kernel), wave-local ----
    int qc = atomicAdd(&qcnt[wave], 0);
    if (qc > QW) qc = QW;
    for (int qi = lane; qi < qc; qi += 64) {
        unsigned e = qbuf[wave * QW + qi];
        int m = (int)(e >> 9), n = (int)(e & 511u);
        const float4* er = (const float4*)(embed + n * VQ_D);
        const float4* xr = (const float4*)&Xs32[m * X32_STR];
        float dot = 0.f;
#pragma unroll
        for (int d4 = 0; d4 < 16; ++d4) {
            float4 ev = er[d4]; float4 xv = xr[d4];
            dot = fmaf(xv.x, ev.x, dot);
            dot = fmaf(xv.y, ev.y, dot);
            dot = fmaf(xv.z, ev.z, dot);
            dot = fmaf(xv.w, ev.w, dot);
        }
        float v = fmaf(-2.f, dot, esq[n]);
        unsigned long long key =
            (((unsigned long long)fenc(v)) << 32) | (unsigned)n;
        atomicMin(&row_best[m], key);   // exact order; equal dist -> smaller n
    }
    __syncthreads();   // barrier 2: all waves' rechecks done

    // ---- outputs: indices + fully-coalesced quantized rows ----
    if (t < ROWS) out_idx[n0 + t] = (float)(unsigned)(row_best[t] & 0xffffffffu);

#pragma unroll
    for (int it = 0; it < 4; ++it) {
        int o   = it * 1024 + t * 4;          // 64 rows x 64 floats, contiguous
        int row = o >> 6;
        int col = o & 63;
        unsigned k = (unsigned)(row_best[row] & 0xffffffffu);
        float4 val = *(const float4*)(embed + k * VQ_D + col);
        *(float4*)(out_q + (size_t)n0 * VQ_D + o) = val;
    }
}

extern "C" void kernel_launch(void* const* d_in, const int* in_sizes, int n_in,
                              void* d_out, int out_size, void* d_ws, size_t ws_size,
                              hipStream_t stream) {
    const float* x     = (const float*)d_in[0];
    const float* embed = (const float*)d_in[1];
    float* out_q   = (float*)d_out;
    float* out_idx = (float*)d_out + (size_t)VQ_N * VQ_D;

    float* esq          = (float*)d_ws;                          // 512 f
    unsigned short* EH  = (unsigned short*)((char*)d_ws + 2048);
    unsigned short* EL  = (unsigned short*)((char*)d_ws + 2048 + VQ_K * VQ_D * 2);

    vq_prep_kernel<<<(VQ_K * VQ_D) / 256, 256, 0, stream>>>(embed, EH, EL, esq);
    vq_mfma_kernel<<<VQ_N / ROWS, 256, 0, stream>>>(x, embed, esq, EH, EL, out_q, out_idx);
}